// Round 16
// baseline (53.969 us; speedup 1.0000x reference)
//
#include <hip/hip_runtime.h>
#include <hip/hip_bf16.h>
#include <math.h>
#include <stdint.h>

#define B_ 4
#define S_ 2048
#define DM_ 512
#define H_ 8
#define DH_ 64
#define DOUT_ 512
#define W_ 8
#define NS_ 2
#define T_ (NS_ + S_)      // 2050 rows per batch in xc
#define M_TOT (B_ * T_)    // 8200
#define M_PAD 8320         // Abf rows (zero-padded; tail frags read to 8207)
#define N3 1536            // q | k | v concatenated columns
#define SCHUNK 16          // s-strip per thread in attn
#define NBLK_A 2080        // convA blocks in merged conv kernel

typedef __attribute__((ext_vector_type(8))) __bf16   bf16x8;
typedef __attribute__((ext_vector_type(4))) float    f32x4;
typedef __attribute__((ext_vector_type(8))) uint16_t u16x8;

__device__ inline uint16_t f2bf(float f) {          // RNE f32 -> bf16
    uint32_t u = __builtin_bit_cast(uint32_t, f);
    u += 0x7FFF + ((u >> 16) & 1);
    return (uint16_t)(u >> 16);
}
__device__ inline float bf2f(uint16_t u) {
    return __builtin_bit_cast(float, (uint32_t)u << 16);
}
__device__ inline void unpk(uint32_t u, float& a, float& b) {   // 2xbf16 -> 2xf32
    a = __builtin_bit_cast(float, u << 16);
    b = __builtin_bit_cast(float, u & 0xFFFF0000u);
}

// ---------------------------------------------------------------------------
// conv_fused: blocks [0, NBLK_A) do convA (xc -> bf16 Abf, zero-padded);
// blocks [NBLK_A, ...) do convB (W transpose+convert -> Bt).
// ---------------------------------------------------------------------------
__global__ __launch_bounds__(256) void conv_fused(
    const float* __restrict__ x, const float* __restrict__ sink,
    const float* __restrict__ Wq, const float* __restrict__ Wk,
    const float* __restrict__ Wv,
    uint16_t* __restrict__ Abf, uint16_t* __restrict__ Bt)
{
    __shared__ float tile[32][65];
    if (blockIdx.x < NBLK_A) {
        size_t id = (size_t)blockIdx.x * 256 + threadIdx.x;   // one 8-elem chunk
        size_t e0 = id * 8;
        int row = (int)(e0 >> 9);
        int col = (int)(e0 & 511);
        u16x8 o;
        if (row < M_TOT) {
            int b = row / T_;
            int t = row - b * T_;
            const float* src = (t < NS_)
                ? &sink[((size_t)b * NS_ + t) * DM_ + col]
                : &x[((size_t)b * S_ + (t - NS_)) * DM_ + col];
            float4 v0 = *(const float4*)src;
            float4 v1 = *(const float4*)(src + 4);
            o[0] = f2bf(v0.x); o[1] = f2bf(v0.y); o[2] = f2bf(v0.z); o[3] = f2bf(v0.w);
            o[4] = f2bf(v1.x); o[5] = f2bf(v1.y); o[6] = f2bf(v1.z); o[7] = f2bf(v1.w);
        } else {
            o = (u16x8)0;
        }
        *(u16x8*)&Abf[e0] = o;
    } else {
        const int bx = blockIdx.x - NBLK_A;           // 0..383
        const int n0 = (bx % 24) * 64, k0 = (bx / 24) * 32;
        const float* Wsrc = (n0 < 512) ? Wq : ((n0 < 1024) ? Wk : Wv);
        const int nb = n0 & 511;
        const int tid = threadIdx.x;
        const int nn = tid & 63, kk = tid >> 6;       // kk 0..3
        #pragma unroll
        for (int i = 0; i < 8; ++i)
            tile[kk + i * 4][nn] = Wsrc[(size_t)(k0 + kk + i * 4) * DOUT_ + nb + nn];
        __syncthreads();
        const int nn2 = tid >> 2, k8 = (tid & 3) * 8;
        u16x8 o;
        #pragma unroll
        for (int j = 0; j < 8; ++j) o[j] = f2bf(tile[k8 + j][nn2]);
        *(u16x8*)&Bt[(size_t)(n0 + nn2) * DM_ + k0 + k8] = o;
    }
}

// ---------------------------------------------------------------------------
// gemm_bf16: y[M][N3](bf16) = Abf[M][512] * Bt[N3][512]^T (+bk on k third)
// r10 proven structure: 128x128 tile, BK=32, 4 waves (2x2), 3-deep staging
// {STAGE(ks+2); vmcnt(8); barrier; COMPUTE(ks); barrier}, swizzled LDS,
// epilogue scratch aliased on buf 0.
// Grid 12x64 = 768 blocks = exactly 3/CU x 256 CU -> SINGLE dispatch round
// (was 780 -> 768+12 two-round tail).  Rows 8192..8199 computed by a
// register-only MFMA tail on the 96 blocks with by<8 (one 16-col fragment
// each, A/B frags direct from global, no LDS/barriers).
// ---------------------------------------------------------------------------
__global__ __launch_bounds__(256) void gemm_bf16(
    const uint16_t* __restrict__ Abf, const uint16_t* __restrict__ Bt,
    const float* __restrict__ bk, uint16_t* __restrict__ y)
{
    __shared__ __align__(16) uint16_t lds[3 * 8192];   // 48 KB total
    const int tid  = threadIdx.x;
    const int wave = tid >> 6, lane = tid & 63;
    const int row0 = blockIdx.y * 128, col0 = blockIdx.x * 128;
    const int wm = wave >> 1, wn = wave & 1;         // 2x2 wave grid
    f32x4 acc[4][4] = {};

    const int srow  = tid >> 2;                      // staging row 0..63
    const int sslot = tid & 3;                       // 16B slot in row

    // issue the 4 global_load_lds for K-step ks into buffer d
    auto STAGE = [&](int ks, int d) {
        const int k0 = ks * 32;
        uint16_t* As = lds + d * 8192;
        uint16_t* Bs = lds + d * 8192 + 4096;
        #pragma unroll
        for (int i = 0; i < 2; ++i) {
            const int r  = i * 64 + srow;
            const int ls = sslot ^ ((r >> 1) & 3);   // inverse swizzle on src
            const uint16_t* ga = Abf + (size_t)(row0 + r) * DM_ + k0 + ls * 8;
            const uint16_t* gb = Bt  + (size_t)(col0 + r) * DM_ + k0 + ls * 8;
            __builtin_amdgcn_global_load_lds(
                (const __attribute__((address_space(1))) void*)ga,
                (__attribute__((address_space(3))) void*)(As + i * 2048 + wave * 512),
                16, 0, 0);
            __builtin_amdgcn_global_load_lds(
                (const __attribute__((address_space(1))) void*)gb,
                (__attribute__((address_space(3))) void*)(Bs + i * 2048 + wave * 512),
                16, 0, 0);
        }
    };

    const int kslot = lane >> 4;                     // which 8-wide k slice
    const int fr    = lane & 15;

    auto COMPUTE = [&](int d) {
        const uint16_t* As = lds + d * 8192;
        const uint16_t* Bs = lds + d * 8192 + 4096;
        bf16x8 af[4], bfr[4];
        #pragma unroll
        for (int mi = 0; mi < 4; ++mi) {
            const int r  = wm * 64 + mi * 16 + fr;
            const int ss = kslot ^ ((r >> 1) & 3);
            af[mi] = *(const bf16x8*)&As[r * 32 + ss * 8];
        }
        #pragma unroll
        for (int ni = 0; ni < 4; ++ni) {
            const int r  = wn * 64 + ni * 16 + fr;
            const int ss = kslot ^ ((r >> 1) & 3);
            bfr[ni] = *(const bf16x8*)&Bs[r * 32 + ss * 8];
        }
        #pragma unroll
        for (int mi = 0; mi < 4; ++mi)
            #pragma unroll
            for (int ni = 0; ni < 4; ++ni)
                acc[mi][ni] = __builtin_amdgcn_mfma_f32_16x16x32_bf16(
                    af[mi], bfr[ni], acc[mi][ni], 0, 0, 0);
    };

    STAGE(0, 0);
    STAGE(1, 1);
    for (int ks = 0; ks < 16; ++ks) {
        if (ks < 14) {
            STAGE(ks + 2, (ks + 2) % 3);
            asm volatile("s_waitcnt vmcnt(8)" ::: "memory");  // stage ks landed
        } else if (ks == 14) {
            asm volatile("s_waitcnt vmcnt(4)" ::: "memory");
        } else {
            asm volatile("s_waitcnt vmcnt(0)" ::: "memory");
        }
        __builtin_amdgcn_s_barrier();
        __builtin_amdgcn_sched_barrier(0);
        COMPUTE(ks % 3);
        __builtin_amdgcn_sched_barrier(0);
        __builtin_amdgcn_s_barrier();
    }

    // ---- epilogue: wave-private LDS transpose (aliased on buf 0; safe
    // after the loop's trailing barrier), coalesced 16B stores ----
    const int fq = lane >> 4;
    float bias[4];
    #pragma unroll
    for (int ni = 0; ni < 4; ++ni) {
        const int col = col0 + wn * 64 + ni * 16 + fr;
        bias[ni] = (col >= 512 && col < 1024) ? bk[col - 512] : 0.f;
    }
    const int rrow = lane >> 3;                      // 0..7   (read row)
    const int rcol = (lane & 7) * 8;                 // 0..56  (read col, 8 el)
    uint16_t* ep = lds + wave * 1152;                // 16*72 per wave
    #pragma unroll
    for (int mi = 0; mi < 4; ++mi) {
        #pragma unroll
        for (int ni = 0; ni < 4; ++ni)
            #pragma unroll
            for (int r4 = 0; r4 < 4; ++r4)
                ep[(fq * 4 + r4) * 72 + ni * 16 + fr] =
                    f2bf(acc[mi][ni][r4] + bias[ni]);
        __builtin_amdgcn_s_waitcnt(0);               // wave-local LDS drain
        #pragma unroll
        for (int it = 0; it < 2; ++it) {
            const int rl  = it * 8 + rrow;
            const int row = row0 + wm * 64 + mi * 16 + rl;
            u16x8 v = *(const u16x8*)&ep[rl * 72 + rcol];
            *(u16x8*)&y[(size_t)row * N3 + col0 + wn * 64 + rcol] = v;
        }
        __builtin_amdgcn_s_waitcnt(0);               // drain reads before reuse
    }

    // ---- tail: rows 8192..8199, one 16-col fragment per block (by<8) ----
    if (blockIdx.y < 8 && wave == 0) {
        const int cf   = blockIdx.y * 12 + blockIdx.x;   // 0..95
        const int colt = cf * 16 + fr;                   // output col
        const int k8   = kslot * 8;
        f32x4 at = {};
        #pragma unroll
        for (int ks = 0; ks < 16; ++ks) {
            bf16x8 a  = *(const bf16x8*)&Abf[(size_t)(8192 + fr) * DM_ + ks * 32 + k8];
            bf16x8 bb = *(const bf16x8*)&Bt[(size_t)colt * DM_ + ks * 32 + k8];
            at = __builtin_amdgcn_mfma_f32_16x16x32_bf16(a, bb, at, 0, 0, 0);
        }
        const float biasT = (colt >= 512 && colt < 1024) ? bk[colt - 512] : 0.f;
        if (fq < 2) {
            #pragma unroll
            for (int r4 = 0; r4 < 4; ++r4) {
                const int row = 8192 + fq * 4 + r4;      // 8192..8199, all real
                y[(size_t)row * N3 + colt] = f2bf(at[r4] + biasT);
            }
        }
    }
}

// ---------------------------------------------------------------------------
// attn: sliding-window over bf16 y. Thread = (b, channel pair {2t,2t+1}),
// strip of SCHUNK s. All y loads are packed uint32 (2xbf16, 4B/lane);
// out store is float2. Per-channel arithmetic identical to prior rounds.
// ---------------------------------------------------------------------------
__global__ __launch_bounds__(256) void attn_kernel(
    const uint16_t* __restrict__ y, const float* __restrict__ pos,
    float* __restrict__ out)
{
    __shared__ float spos[DH_ * (NS_ + W_)];
    for (int i = threadIdx.x; i < DH_ * (NS_ + W_); i += 256) spos[i] = pos[i];
    __syncthreads();

    const int c0 = threadIdx.x * 2;             // channels c0, c0+1
    const int b  = blockIdx.y;
    const int s0 = blockIdx.x * SCHUNK;
    const uint16_t* yb = y + (size_t)b * T_ * N3;
    const int dh = c0 & (DH_ - 1);              // even; pair dh = {dh, dh+1}

    float ppA[NS_ + W_], ppB[NS_ + W_];
    #pragma unroll
    for (int p = 0; p < NS_ + W_; ++p) {
        ppA[p] = spos[dh * (NS_ + W_) + p];
        ppB[p] = spos[(dh + 1) * (NS_ + W_) + p];
    }

    float sqA0, sqB0, sqA1, sqB1, svA0, svB0, svA1, svB1;
    unpk(*(const uint32_t*)(yb + 0 * N3 + c0),        sqA0, sqB0);
    unpk(*(const uint32_t*)(yb + 1 * N3 + c0),        sqA1, sqB1);
    unpk(*(const uint32_t*)(yb + 0 * N3 + 1024 + c0), svA0, svB0);
    unpk(*(const uint32_t*)(yb + 1 * N3 + 1024 + c0), svA1, svB1);

    float qA[W_], qB[W_], vA[W_], vB[W_];
    #pragma unroll
    for (int j = 0; j < W_ - 1; ++j) {
        const uint16_t* rq = yb + (size_t)(NS_ + s0 + j) * N3 + c0;
        unpk(*(const uint32_t*)rq,          qA[j], qB[j]);
        unpk(*(const uint32_t*)(rq + 1024), vA[j], vB[j]);
    }

    for (int i = 0; i < SCHUNK; ++i) {
        const int s = s0 + i;
        int tq = NS_ + s + (W_ - 1);
        if (tq > T_ - 1) tq = T_ - 1;            // clamp (masked below)
        const uint16_t* rq = yb + (size_t)tq * N3 + c0;
        unpk(*(const uint32_t*)rq,          qA[W_ - 1], qB[W_ - 1]);
        unpk(*(const uint32_t*)(rq + 1024), vA[W_ - 1], vB[W_ - 1]);
        float kvA, kvB;
        unpk(*(const uint32_t*)(yb + (size_t)(NS_ + s) * N3 + 512 + c0), kvA, kvB);

        float scA[NS_ + W_], scB[NS_ + W_];
        scA[0] = (sqA0 + ppA[0]) * kvA;  scB[0] = (sqB0 + ppB[0]) * kvB;
        scA[1] = (sqA1 + ppA[1]) * kvA;  scB[1] = (sqB1 + ppB[1]) * kvB;
        #pragma unroll
        for (int r = 0; r < W_; ++r) {
            scA[NS_ + r] = (qA[r] + ppA[NS_ + r]) * kvA;
            scB[NS_ + r] = (qB[r] + ppB[NS_ + r]) * kvB;
        }
        if (s > S_ - W_) {                       // tail masking (uniform)
            const int nv = S_ - s;
            #pragma unroll
            for (int r = 0; r < W_; ++r)
                if (r >= nv) { scA[NS_ + r] = -INFINITY; scB[NS_ + r] = -INFINITY; }
        }

        float mA = scA[0], mB = scB[0];
        #pragma unroll
        for (int p = 1; p < NS_ + W_; ++p) {
            mA = fmaxf(mA, scA[p]); mB = fmaxf(mB, scB[p]);
        }
        float sumA = 0.f, sumB = 0.f, accA, accB;
        float eA[NS_ + W_], eB[NS_ + W_];
        #pragma unroll
        for (int p = 0; p < NS_ + W_; ++p) {
            eA[p] = __expf(scA[p] - mA); sumA += eA[p];
            eB[p] = __expf(scB[p] - mB); sumB += eB[p];
        }
        accA = eA[0] * svA0 + eA[1] * svA1;
        accB = eB[0] * svB0 + eB[1] * svB1;
        #pragma unroll
        for (int r = 0; r < W_; ++r) {
            accA = fmaf(eA[NS_ + r], vA[r], accA);
            accB = fmaf(eB[NS_ + r], vB[r], accB);
        }

        float2 o = make_float2(accA / sumA, accB / sumB);
        *(float2*)&out[((size_t)b * S_ + s) * DOUT_ + c0] = o;

        #pragma unroll
        for (int j = 0; j < W_ - 1; ++j) {
            qA[j] = qA[j + 1]; qB[j] = qB[j + 1];
            vA[j] = vA[j + 1]; vB[j] = vB[j + 1];
        }
    }
}

// ---------------------------------------------------------------------------
extern "C" void kernel_launch(void* const* d_in, const int* in_sizes, int n_in,
                              void* d_out, int out_size, void* d_ws, size_t ws_size,
                              hipStream_t stream) {
    const float* x    = (const float*)d_in[0];
    const float* sink = (const float*)d_in[1];
    const float* Wk   = (const float*)d_in[2];
    const float* bk   = (const float*)d_in[3];
    const float* Wq   = (const float*)d_in[4];
    const float* Wv   = (const float*)d_in[5];
    const float* pos  = (const float*)d_in[6];

    char* ws = (char*)d_ws;
    uint16_t* y   = (uint16_t*)ws;                                // 25,190,400 B
    uint16_t* Abf = (uint16_t*)(ws + (size_t)M_TOT * N3 * 2);     //  8,519,680 B
    uint16_t* Bt  = (uint16_t*)(ws + (size_t)M_TOT * N3 * 2
                                   + (size_t)M_PAD * DM_ * 2);    //  1,572,864 B

    conv_fused<<<dim3(NBLK_A + 384), 256, 0, stream>>>(x, sink, Wq, Wk, Wv, Abf, Bt);
    gemm_bf16<<<dim3(12, 64), 256, 0, stream>>>(Abf, Bt, bk, y);
    attn_kernel<<<dim3(S_ / SCHUNK, B_), 256, 0, stream>>>(y, pos, (float*)d_out);
}

// Round 17
// 52.302 us; speedup vs baseline: 1.0319x; 1.0319x over previous
//
#include <hip/hip_runtime.h>
#include <hip/hip_bf16.h>
#include <math.h>
#include <stdint.h>

#define B_ 4
#define S_ 2048
#define DM_ 512
#define H_ 8
#define DH_ 64
#define DOUT_ 512
#define W_ 8
#define NS_ 2
#define T_ (NS_ + S_)      // 2050 rows per batch in xc
#define M_TOT (B_ * T_)    // 8200
#define M_PAD 8320         // 65 * 128, zero-padded tail
#define N3 1536            // q | k | v concatenated columns
#define SCHUNK 16          // s-strip per thread in attn
#define NBLK_A 2080        // convA blocks in merged conv kernel

typedef __attribute__((ext_vector_type(8))) __bf16   bf16x8;
typedef __attribute__((ext_vector_type(4))) float    f32x4;
typedef __attribute__((ext_vector_type(8))) uint16_t u16x8;

__device__ inline uint16_t f2bf(float f) {          // RNE f32 -> bf16
    uint32_t u = __builtin_bit_cast(uint32_t, f);
    u += 0x7FFF + ((u >> 16) & 1);
    return (uint16_t)(u >> 16);
}
__device__ inline float bf2f(uint16_t u) {
    return __builtin_bit_cast(float, (uint32_t)u << 16);
}
__device__ inline void unpk(uint32_t u, float& a, float& b) {   // 2xbf16 -> 2xf32
    a = __builtin_bit_cast(float, u << 16);
    b = __builtin_bit_cast(float, u & 0xFFFF0000u);
}

// ---------------------------------------------------------------------------
// conv_fused: blocks [0, NBLK_A) do convA (xc -> bf16 Abf, zero-padded);
// blocks [NBLK_A, ...) do convB (W transpose+convert -> Bt).
// ---------------------------------------------------------------------------
__global__ __launch_bounds__(256) void conv_fused(
    const float* __restrict__ x, const float* __restrict__ sink,
    const float* __restrict__ Wq, const float* __restrict__ Wk,
    const float* __restrict__ Wv,
    uint16_t* __restrict__ Abf, uint16_t* __restrict__ Bt)
{
    __shared__ float tile[32][65];
    if (blockIdx.x < NBLK_A) {
        size_t id = (size_t)blockIdx.x * 256 + threadIdx.x;   // one 8-elem chunk
        size_t e0 = id * 8;
        int row = (int)(e0 >> 9);
        int col = (int)(e0 & 511);
        u16x8 o;
        if (row < M_TOT) {
            int b = row / T_;
            int t = row - b * T_;
            const float* src = (t < NS_)
                ? &sink[((size_t)b * NS_ + t) * DM_ + col]
                : &x[((size_t)b * S_ + (t - NS_)) * DM_ + col];
            float4 v0 = *(const float4*)src;
            float4 v1 = *(const float4*)(src + 4);
            o[0] = f2bf(v0.x); o[1] = f2bf(v0.y); o[2] = f2bf(v0.z); o[3] = f2bf(v0.w);
            o[4] = f2bf(v1.x); o[5] = f2bf(v1.y); o[6] = f2bf(v1.z); o[7] = f2bf(v1.w);
        } else {
            o = (u16x8)0;
        }
        *(u16x8*)&Abf[e0] = o;
    } else {
        const int bx = blockIdx.x - NBLK_A;           // 0..383
        const int n0 = (bx % 24) * 64, k0 = (bx / 24) * 32;
        const float* Wsrc = (n0 < 512) ? Wq : ((n0 < 1024) ? Wk : Wv);
        const int nb = n0 & 511;
        const int tid = threadIdx.x;
        const int nn = tid & 63, kk = tid >> 6;       // kk 0..3
        #pragma unroll
        for (int i = 0; i < 8; ++i)
            tile[kk + i * 4][nn] = Wsrc[(size_t)(k0 + kk + i * 4) * DOUT_ + nb + nn];
        __syncthreads();
        const int nn2 = tid >> 2, k8 = (tid & 3) * 8;
        u16x8 o;
        #pragma unroll
        for (int j = 0; j < 8; ++j) o[j] = f2bf(tile[k8 + j][nn2]);
        *(u16x8*)&Bt[(size_t)(n0 + nn2) * DM_ + k0 + k8] = o;
    }
}

// ---------------------------------------------------------------------------
// gemm_bf16: y[M][N3](bf16) = Abf[M][512] * Bt[N3][512]^T (+bk on k third)
// r10 proven structure: 128x128 tile, BK=32, 4 waves (2x2), 3-deep staging
// {STAGE(ks+2); vmcnt(8); barrier; COMPUTE(ks); barrier}, global_load_lds
// w=16, swizzled LDS, epilogue scratch aliased on buf 0.
// (Single-barrier variants r13/r14 raced nondeterministically -- abandoned.
//  Grid reshaping r16 regressed -- reverted.)
// ---------------------------------------------------------------------------
__global__ __launch_bounds__(256) void gemm_bf16(
    const uint16_t* __restrict__ Abf, const uint16_t* __restrict__ Bt,
    const float* __restrict__ bk, uint16_t* __restrict__ y)
{
    __shared__ __align__(16) uint16_t lds[3 * 8192];   // 48 KB total
    const int tid  = threadIdx.x;
    const int wave = tid >> 6, lane = tid & 63;
    const int row0 = blockIdx.y * 128, col0 = blockIdx.x * 128;
    const int wm = wave >> 1, wn = wave & 1;         // 2x2 wave grid
    f32x4 acc[4][4] = {};

    const int srow  = tid >> 2;                      // staging row 0..63
    const int sslot = tid & 3;                       // 16B slot in row

    // issue the 4 global_load_lds for K-step ks into buffer d
    auto STAGE = [&](int ks, int d) {
        const int k0 = ks * 32;
        uint16_t* As = lds + d * 8192;
        uint16_t* Bs = lds + d * 8192 + 4096;
        #pragma unroll
        for (int i = 0; i < 2; ++i) {
            const int r  = i * 64 + srow;
            const int ls = sslot ^ ((r >> 1) & 3);   // inverse swizzle on src
            const uint16_t* ga = Abf + (size_t)(row0 + r) * DM_ + k0 + ls * 8;
            const uint16_t* gb = Bt  + (size_t)(col0 + r) * DM_ + k0 + ls * 8;
            __builtin_amdgcn_global_load_lds(
                (const __attribute__((address_space(1))) void*)ga,
                (__attribute__((address_space(3))) void*)(As + i * 2048 + wave * 512),
                16, 0, 0);
            __builtin_amdgcn_global_load_lds(
                (const __attribute__((address_space(1))) void*)gb,
                (__attribute__((address_space(3))) void*)(Bs + i * 2048 + wave * 512),
                16, 0, 0);
        }
    };

    const int kslot = lane >> 4;                     // which 8-wide k slice
    const int fr    = lane & 15;

    auto COMPUTE = [&](int d) {
        const uint16_t* As = lds + d * 8192;
        const uint16_t* Bs = lds + d * 8192 + 4096;
        bf16x8 af[4], bfr[4];
        #pragma unroll
        for (int mi = 0; mi < 4; ++mi) {
            const int r  = wm * 64 + mi * 16 + fr;
            const int ss = kslot ^ ((r >> 1) & 3);
            af[mi] = *(const bf16x8*)&As[r * 32 + ss * 8];
        }
        #pragma unroll
        for (int ni = 0; ni < 4; ++ni) {
            const int r  = wn * 64 + ni * 16 + fr;
            const int ss = kslot ^ ((r >> 1) & 3);
            bfr[ni] = *(const bf16x8*)&Bs[r * 32 + ss * 8];
        }
        #pragma unroll
        for (int mi = 0; mi < 4; ++mi)
            #pragma unroll
            for (int ni = 0; ni < 4; ++ni)
                acc[mi][ni] = __builtin_amdgcn_mfma_f32_16x16x32_bf16(
                    af[mi], bfr[ni], acc[mi][ni], 0, 0, 0);
    };

    STAGE(0, 0);
    STAGE(1, 1);
    for (int ks = 0; ks < 16; ++ks) {
        if (ks < 14) {
            STAGE(ks + 2, (ks + 2) % 3);
            asm volatile("s_waitcnt vmcnt(8)" ::: "memory");  // stage ks landed
        } else if (ks == 14) {
            asm volatile("s_waitcnt vmcnt(4)" ::: "memory");
        } else {
            asm volatile("s_waitcnt vmcnt(0)" ::: "memory");
        }
        __builtin_amdgcn_s_barrier();
        __builtin_amdgcn_sched_barrier(0);
        COMPUTE(ks % 3);
        __builtin_amdgcn_sched_barrier(0);
        __builtin_amdgcn_s_barrier();
    }

    // ---- epilogue: wave-private LDS transpose (aliased on buf 0; safe
    // after the loop's trailing barrier), coalesced 16B stores ----
    const int fq = lane >> 4;
    float bias[4];
    #pragma unroll
    for (int ni = 0; ni < 4; ++ni) {
        const int col = col0 + wn * 64 + ni * 16 + fr;
        bias[ni] = (col >= 512 && col < 1024) ? bk[col - 512] : 0.f;
    }
    const int rrow = lane >> 3;                      // 0..7   (read row)
    const int rcol = (lane & 7) * 8;                 // 0..56  (read col, 8 el)
    uint16_t* ep = lds + wave * 1152;                // 16*72 per wave
    #pragma unroll
    for (int mi = 0; mi < 4; ++mi) {
        #pragma unroll
        for (int ni = 0; ni < 4; ++ni)
            #pragma unroll
            for (int r4 = 0; r4 < 4; ++r4)
                ep[(fq * 4 + r4) * 72 + ni * 16 + fr] =
                    f2bf(acc[mi][ni][r4] + bias[ni]);
        __builtin_amdgcn_s_waitcnt(0);               // wave-local LDS drain
        #pragma unroll
        for (int it = 0; it < 2; ++it) {
            const int rl  = it * 8 + rrow;
            const int row = row0 + wm * 64 + mi * 16 + rl;
            u16x8 v = *(const u16x8*)&ep[rl * 72 + rcol];
            if (row < M_TOT)
                *(u16x8*)&y[(size_t)row * N3 + col0 + wn * 64 + rcol] = v;
        }
        __builtin_amdgcn_s_waitcnt(0);               // drain reads before reuse
    }
}

// ---------------------------------------------------------------------------
// attn: sliding-window over bf16 y. Thread = (b, channel pair {2t,2t+1}),
// strip of SCHUNK s. All y loads are packed uint32 (2xbf16, 4B/lane);
// out store is float2. Per-channel arithmetic identical to prior rounds.
// ---------------------------------------------------------------------------
__global__ __launch_bounds__(256) void attn_kernel(
    const uint16_t* __restrict__ y, const float* __restrict__ pos,
    float* __restrict__ out)
{
    __shared__ float spos[DH_ * (NS_ + W_)];
    for (int i = threadIdx.x; i < DH_ * (NS_ + W_); i += 256) spos[i] = pos[i];
    __syncthreads();

    const int c0 = threadIdx.x * 2;             // channels c0, c0+1
    const int b  = blockIdx.y;
    const int s0 = blockIdx.x * SCHUNK;
    const uint16_t* yb = y + (size_t)b * T_ * N3;
    const int dh = c0 & (DH_ - 1);              // even; pair dh = {dh, dh+1}

    float ppA[NS_ + W_], ppB[NS_ + W_];
    #pragma unroll
    for (int p = 0; p < NS_ + W_; ++p) {
        ppA[p] = spos[dh * (NS_ + W_) + p];
        ppB[p] = spos[(dh + 1) * (NS_ + W_) + p];
    }

    float sqA0, sqB0, sqA1, sqB1, svA0, svB0, svA1, svB1;
    unpk(*(const uint32_t*)(yb + 0 * N3 + c0),        sqA0, sqB0);
    unpk(*(const uint32_t*)(yb + 1 * N3 + c0),        sqA1, sqB1);
    unpk(*(const uint32_t*)(yb + 0 * N3 + 1024 + c0), svA0, svB0);
    unpk(*(const uint32_t*)(yb + 1 * N3 + 1024 + c0), svA1, svB1);

    float qA[W_], qB[W_], vA[W_], vB[W_];
    #pragma unroll
    for (int j = 0; j < W_ - 1; ++j) {
        const uint16_t* rq = yb + (size_t)(NS_ + s0 + j) * N3 + c0;
        unpk(*(const uint32_t*)rq,          qA[j], qB[j]);
        unpk(*(const uint32_t*)(rq + 1024), vA[j], vB[j]);
    }

    for (int i = 0; i < SCHUNK; ++i) {
        const int s = s0 + i;
        int tq = NS_ + s + (W_ - 1);
        if (tq > T_ - 1) tq = T_ - 1;            // clamp (masked below)
        const uint16_t* rq = yb + (size_t)tq * N3 + c0;
        unpk(*(const uint32_t*)rq,          qA[W_ - 1], qB[W_ - 1]);
        unpk(*(const uint32_t*)(rq + 1024), vA[W_ - 1], vB[W_ - 1]);
        float kvA, kvB;
        unpk(*(const uint32_t*)(yb + (size_t)(NS_ + s) * N3 + 512 + c0), kvA, kvB);

        float scA[NS_ + W_], scB[NS_ + W_];
        scA[0] = (sqA0 + ppA[0]) * kvA;  scB[0] = (sqB0 + ppB[0]) * kvB;
        scA[1] = (sqA1 + ppA[1]) * kvA;  scB[1] = (sqB1 + ppB[1]) * kvB;
        #pragma unroll
        for (int r = 0; r < W_; ++r) {
            scA[NS_ + r] = (qA[r] + ppA[NS_ + r]) * kvA;
            scB[NS_ + r] = (qB[r] + ppB[NS_ + r]) * kvB;
        }
        if (s > S_ - W_) {                       // tail masking (uniform)
            const int nv = S_ - s;
            #pragma unroll
            for (int r = 0; r < W_; ++r)
                if (r >= nv) { scA[NS_ + r] = -INFINITY; scB[NS_ + r] = -INFINITY; }
        }

        float mA = scA[0], mB = scB[0];
        #pragma unroll
        for (int p = 1; p < NS_ + W_; ++p) {
            mA = fmaxf(mA, scA[p]); mB = fmaxf(mB, scB[p]);
        }
        float sumA = 0.f, sumB = 0.f, accA, accB;
        float eA[NS_ + W_], eB[NS_ + W_];
        #pragma unroll
        for (int p = 0; p < NS_ + W_; ++p) {
            eA[p] = __expf(scA[p] - mA); sumA += eA[p];
            eB[p] = __expf(scB[p] - mB); sumB += eB[p];
        }
        accA = eA[0] * svA0 + eA[1] * svA1;
        accB = eB[0] * svB0 + eB[1] * svB1;
        #pragma unroll
        for (int r = 0; r < W_; ++r) {
            accA = fmaf(eA[NS_ + r], vA[r], accA);
            accB = fmaf(eB[NS_ + r], vB[r], accB);
        }

        float2 o = make_float2(accA / sumA, accB / sumB);
        *(float2*)&out[((size_t)b * S_ + s) * DOUT_ + c0] = o;

        #pragma unroll
        for (int j = 0; j < W_ - 1; ++j) {
            qA[j] = qA[j + 1]; qB[j] = qB[j + 1];
            vA[j] = vA[j + 1]; vB[j] = vB[j + 1];
        }
    }
}

// ---------------------------------------------------------------------------
extern "C" void kernel_launch(void* const* d_in, const int* in_sizes, int n_in,
                              void* d_out, int out_size, void* d_ws, size_t ws_size,
                              hipStream_t stream) {
    const float* x    = (const float*)d_in[0];
    const float* sink = (const float*)d_in[1];
    const float* Wk   = (const float*)d_in[2];
    const float* bk   = (const float*)d_in[3];
    const float* Wq   = (const float*)d_in[4];
    const float* Wv   = (const float*)d_in[5];
    const float* pos  = (const float*)d_in[6];

    char* ws = (char*)d_ws;
    uint16_t* y   = (uint16_t*)ws;                                // 25,190,400 B
    uint16_t* Abf = (uint16_t*)(ws + (size_t)M_TOT * N3 * 2);     //  8,519,680 B
    uint16_t* Bt  = (uint16_t*)(ws + (size_t)M_TOT * N3 * 2
                                   + (size_t)M_PAD * DM_ * 2);    //  1,572,864 B

    conv_fused<<<dim3(NBLK_A + 384), 256, 0, stream>>>(x, sink, Wq, Wk, Wv, Abf, Bt);
    gemm_bf16<<<dim3(12, 65), 256, 0, stream>>>(Abf, Bt, bk, y);
    attn_kernel<<<dim3(S_ / SCHUNK, B_), 256, 0, stream>>>(y, pos, (float*)d_out);
}